// Round 3
// baseline (362.852 us; speedup 1.0000x reference)
//
#include <hip/hip_runtime.h>

// Streaming read of only the needed 32 B/row (float4 parts 1 and 2), LDS
// redistribute, dense float4 output stores. 512 rows per 256-thread block.
// Needed float4 index for j in [0,1024): idx = 4*(j>>1) + 1 + (j&1)
//   part 1 -> cols 4..7 -> diff; part 2 -> cols 8..11 -> trend = .w
__global__ __launch_bounds__(256) void gating_kernel(
    const float* __restrict__ feat, float* __restrict__ out) {
    constexpr int ROWS = 512;
    __shared__ float s_diff[ROWS];
    __shared__ float s_trend[ROWS];
    __shared__ float s_out[3 * ROWS];

    const int t = threadIdx.x;
    const size_t row0 = (size_t)blockIdx.x * ROWS;
    const float4* in4 = reinterpret_cast<const float4*>(feat) + row0 * 4;

#pragma unroll
    for (int k = 0; k < 4; ++k) {
        const int j = t + k * 256;           // 1024 needed float4s per tile
        const int r = j >> 1;                // row within tile
        const float4 v = in4[4 * r + 1 + (j & 1)];
        if (j & 1) s_trend[r] = v.w;                          // col 11
        else       s_diff[r]  = (v.x + v.y) - (v.z + v.w);    // (c4+c5)-(c6+c7)
    }
    __syncthreads();

#pragma unroll
    for (int k = 0; k < 2; ++k) {
        const int r = t + k * 256;
        const bool s0 = s_trend[r] > 0.5f;
        const bool s1 = s_diff[r] > 0.0f;
        s_out[3 * r + 0] = s0 ? 1.0f : 0.0f;
        s_out[3 * r + 1] = (!s0 && s1) ? 1.0f : 0.0f;
        s_out[3 * r + 2] = (!s0 && !s1) ? 1.0f : 0.0f;
    }
    __syncthreads();

    // 512 rows * 3 = 1536 floats = 384 float4 stores
    float4* ob = reinterpret_cast<float4*>(out + row0 * 3);
    const float4* so4 = reinterpret_cast<const float4*>(s_out);
    ob[t] = so4[t];
    if (t < 128) ob[256 + t] = so4[256 + t];
}

extern "C" void kernel_launch(void* const* d_in, const int* in_sizes, int n_in,
                              void* d_out, int out_size, void* d_ws, size_t ws_size,
                              hipStream_t stream) {
    const float* feat = (const float*)d_in[0];
    float* out = (float*)d_out;

    const int n_rows = in_sizes[0] / 16;   // 4194304, divisible by 512
    const int grid = n_rows / 512;         // 8192 blocks

    gating_kernel<<<grid, 256, 0, stream>>>(feat, out);
}